// Round 4
// baseline (2627.135 us; speedup 1.0000x reference)
//
#include <hip/hip_runtime.h>
#include <math.h>

// ---------------------------------------------------------------------------
// B=16, NP1=65, BT=1040 tokens, Mg=256, D=512, H=8, DH=64, L=3, DFF=2048
// R4: persistent mega-kernel (256 blocks = 1/CU, co-resident) with grid
// barriers; register-direct MFMA GEMM phases (no LDS, no barriers in K-loop).
// 3 graph nodes total: memset(bar) + cvt_weights + mega.
// ---------------------------------------------------------------------------

#define BT   1040
#define NP1  65
#define Dm   512
#define MG   256
#define NBLK 256
#define NW   1024   // total waves = NBLK * 4

typedef short short8 __attribute__((ext_vector_type(8)));
typedef float f32x4  __attribute__((ext_vector_type(4)));
typedef unsigned short u16;

__device__ __forceinline__ u16 f2bf(float f) {
  unsigned int u = __float_as_uint(f);
  u += 0x7FFF + ((u >> 16) & 1);          // RNE
  return (u16)(u >> 16);
}

__device__ __forceinline__ float gelu_exact(float x) {
  return 0.5f * x * (1.0f + erff(x * 0.70710678118654752f));
}

__device__ __forceinline__ float wred(float v) {
#pragma unroll
  for (int o = 32; o; o >>= 1) v += __shfl_xor(v, o, 64);
  return v;
}

// grid barrier: all NBLK blocks co-resident (1/CU). bar[0]=count, bar[1]=gen.
__device__ __forceinline__ void gbar(unsigned* bar) {
  __threadfence();                                   // release my writes
  __syncthreads();
  if (threadIdx.x == 0) {
    unsigned gen = __hip_atomic_load(&bar[1], __ATOMIC_RELAXED, __HIP_MEMORY_SCOPE_AGENT);
    unsigned arr = __hip_atomic_fetch_add(&bar[0], 1u, __ATOMIC_ACQ_REL, __HIP_MEMORY_SCOPE_AGENT);
    if (arr == (unsigned)NBLK - 1) {
      __hip_atomic_store(&bar[0], 0u, __ATOMIC_RELAXED, __HIP_MEMORY_SCOPE_AGENT);
      __hip_atomic_fetch_add(&bar[1], 1u, __ATOMIC_ACQ_REL, __HIP_MEMORY_SCOPE_AGENT);
    } else {
      while (__hip_atomic_load(&bar[1], __ATOMIC_ACQUIRE, __HIP_MEMORY_SCOPE_AGENT) == gen)
        __builtin_amdgcn_s_sleep(2);
    }
  }
  __syncthreads();
  __threadfence();                                   // acquire others' writes
}

// ---------------------------------------------------------------------------
// register-direct 64x64 wave GEMM tile: acc += A[row0..+64, k0..] * B^T
// A,B bf16 row-major (lda/ldb in elements). KC = number of 32-wide k-chunks.
// Fragment layout (verified R2/R3): lane=(q<<4)|l15 holds A[m=l15][k=c*32+q*8+j]
// ---------------------------------------------------------------------------
__device__ __forceinline__ void gemm_tile64(
    const u16* __restrict__ A, int lda, const u16* __restrict__ Bt, int ldb,
    int row0, int KC, f32x4 acc[4][4], int lane)
{
  const int l15 = lane & 15, q = lane >> 4;
  const u16* ap[4];
  const u16* bp[4];
#pragma unroll
  for (int mi = 0; mi < 4; ++mi)
    ap[mi] = A + (size_t)min(row0 + mi * 16 + l15, BT - 1) * lda + q * 8;
#pragma unroll
  for (int ni = 0; ni < 4; ++ni)
    bp[ni] = Bt + (size_t)(ni * 16 + l15) * ldb + q * 8;
#pragma unroll 2
  for (int c = 0; c < KC; ++c) {
    short8 af[4], bf[4];
#pragma unroll
    for (int mi = 0; mi < 4; ++mi) af[mi] = *(const short8*)(ap[mi] + c * 32);
#pragma unroll
    for (int ni = 0; ni < 4; ++ni) bf[ni] = *(const short8*)(bp[ni] + c * 32);
#pragma unroll
    for (int mi = 0; mi < 4; ++mi)
#pragma unroll
      for (int ni = 0; ni < 4; ++ni)
        acc[mi][ni] = __builtin_amdgcn_mfma_f32_16x16x32_bf16(
            af[mi], bf[ni], acc[mi][ni], 0, 0, 0);
  }
}

#define ZERO_ACC(acc) \
  { _Pragma("unroll") for (int zi = 0; zi < 4; ++zi) \
    _Pragma("unroll") for (int zj = 0; zj < 4; ++zj) \
      acc[zi][zj] = (f32x4){0.f, 0.f, 0.f, 0.f}; }

// ---------------------------------------------------------------------------
// weight fp32 -> bf16 (offsets in u16: qkv 0 | out 2359296 | ff1 3145728 |
// ff2 6291456 | uh 9437184 | total 9699328)
// ---------------------------------------------------------------------------
__global__ __launch_bounds__(256) void cvt_weights(
    const float* __restrict__ qkv_w, const float* __restrict__ out_w,
    const float* __restrict__ ff1_w, const float* __restrict__ ff2_w,
    const float* __restrict__ u_w,   const float* __restrict__ h_w,
    u16* __restrict__ dst)
{
  const size_t O1 = 2359296, O2 = 3145728, O3 = 6291456;
  const size_t O4 = 9437184, O5 = 9568256, TOT4 = 9699328 / 4;
  for (size_t e4 = (size_t)blockIdx.x * 256 + threadIdx.x; e4 < TOT4;
       e4 += (size_t)gridDim.x * 256) {
    size_t e = e4 * 4;
    const float* src;
    if      (e < O1) src = qkv_w + e;
    else if (e < O2) src = out_w + (e - O1);
    else if (e < O3) src = ff1_w + (e - O2);
    else if (e < O4) src = ff2_w + (e - O3);
    else if (e < O5) src = u_w   + (e - O4);
    else             src = h_w   + (e - O5);
    float4 v = *(const float4*)src;
    unsigned int lo = (unsigned int)f2bf(v.x) | ((unsigned int)f2bf(v.y) << 16);
    unsigned int hi = (unsigned int)f2bf(v.z) | ((unsigned int)f2bf(v.w) << 16);
    *(uint2*)(dst + e) = make_uint2(lo, hi);
  }
}

// ---------------------------------------------------------------------------
// THE MEGA KERNEL
// ---------------------------------------------------------------------------
__global__ __launch_bounds__(256, 1) void mega(
    const float* __restrict__ marg, const float* __restrict__ xg,
    const float* __restrict__ conv_w, const float* __restrict__ conv_b,
    const float* __restrict__ fc_w, const float* __restrict__ fc_b,
    const float* __restrict__ ln0_g, const float* __restrict__ ln0_b,
    const float* __restrict__ pos, const float* __restrict__ qkv_b,
    const float* __restrict__ out_b, const float* __restrict__ ln1_g,
    const float* __restrict__ ln1_b, const float* __restrict__ ff1_b,
    const float* __restrict__ ff2_b, const float* __restrict__ ln2_g,
    const float* __restrict__ ln2_b, const float* __restrict__ u_b,
    const float* __restrict__ h_b, const u16* __restrict__ wbf,
    float* __restrict__ xs, u16* __restrict__ xsb,
    float* __restrict__ qkvbuf, u16* __restrict__ obufb,
    u16* __restrict__ ffb, float* __restrict__ part,
    float* __restrict__ hbuf, float* __restrict__ out_u,
    float* __restrict__ out_h, unsigned* __restrict__ bar)
{
  __shared__ union {
    struct { float qv[65][67]; float ks[65][67]; float ss[65][67]; } at;
    float xgs[256];
  } sm;

  const int tid  = threadIdx.x, bid = blockIdx.x;
  const int lane = tid & 63,   wave = tid >> 6;
  const int gw   = bid * 4 + wave;
  const int l15  = lane & 15,  q    = lane >> 4;

  // ===== Phase E: conv+mean (collapsed) -> fc -> LN -> GELU -> +pos =====
  for (int t = gw; t < BT; t += NW) {
    const float* row = marg + (size_t)t * MG;
    float4 mv = *(const float4*)(row + lane * 4);
    float S = wred(mv.x + mv.y + mv.z + mv.w);
    float x0 = row[0], x1 = row[1], x254 = row[254], x255 = row[255];
    int c0 = lane * 8;
    float z[8];
    {
      float4 b0 = *(const float4*)(fc_b + c0), b1 = *(const float4*)(fc_b + c0 + 4);
      z[0]=b0.x; z[1]=b0.y; z[2]=b0.z; z[3]=b0.w;
      z[4]=b1.x; z[5]=b1.y; z[6]=b1.z; z[7]=b1.w;
    }
    for (int o = 0; o < 128; ++o) {
      float w0 = conv_w[o*5+0], w1 = conv_w[o*5+1], w2 = conv_w[o*5+2];
      float w3 = conv_w[o*5+3], w4 = conv_w[o*5+4];
      float e = (w0*(S - x254 - x255) + w1*(S - x255) + w2*S
               + w3*(S - x0) + w4*(S - x0 - x1)) * (1.0f/256.0f) + conv_b[o];
      float4 f0 = *(const float4*)(fc_w + (size_t)o*Dm + c0);
      float4 f1 = *(const float4*)(fc_w + (size_t)o*Dm + c0 + 4);
      z[0] += e*f0.x; z[1] += e*f0.y; z[2] += e*f0.z; z[3] += e*f0.w;
      z[4] += e*f1.x; z[5] += e*f1.y; z[6] += e*f1.z; z[7] += e*f1.w;
    }
    float s1 = 0.f;
#pragma unroll
    for (int j = 0; j < 8; ++j) s1 += z[j];
    float mu = wred(s1) * (1.0f/512.0f);
    float s2 = 0.f;
#pragma unroll
    for (int j = 0; j < 8; ++j) { float d = z[j] - mu; s2 += d * d; }
    float inv = rsqrtf(wred(s2) * (1.0f/512.0f) + 1e-5f);
    int p = t % NP1;
    float4 g0 = *(const float4*)(ln0_g + c0), g1 = *(const float4*)(ln0_g + c0 + 4);
    float4 e0 = *(const float4*)(ln0_b + c0), e1 = *(const float4*)(ln0_b + c0 + 4);
    float4 p0 = *(const float4*)(pos + (size_t)p*Dm + c0);
    float4 p1 = *(const float4*)(pos + (size_t)p*Dm + c0 + 4);
    float gg[8] = {g0.x,g0.y,g0.z,g0.w,g1.x,g1.y,g1.z,g1.w};
    float ee[8] = {e0.x,e0.y,e0.z,e0.w,e1.x,e1.y,e1.z,e1.w};
    float pp[8] = {p0.x,p0.y,p0.z,p0.w,p1.x,p1.y,p1.z,p1.w};
    float y[8]; u16 yb[8];
#pragma unroll
    for (int j = 0; j < 8; ++j) {
      y[j] = gelu_exact((z[j] - mu) * inv * gg[j] + ee[j]) + pp[j];
      yb[j] = f2bf(y[j]);
    }
    *(float4*)(xs + (size_t)t*Dm + c0)     = make_float4(y[0],y[1],y[2],y[3]);
    *(float4*)(xs + (size_t)t*Dm + c0 + 4) = make_float4(y[4],y[5],y[6],y[7]);
    *(short8*)(xsb + (size_t)t*Dm + c0)    = *(short8*)yb;
  }
  gbar(bar);

  // ===== 3 transformer layers =====
  for (int l = 0; l < 3; ++l) {
    // ---- qkv GEMM: [1040,512]bf16 x [1536,512]^T -> qkvbuf fp32 ----
    {
      const u16* qW = wbf + (size_t)l * 786432;
      const float* qb = qkv_b + l * 1536;
      for (int t = gw; t < 17 * 24; t += NW) {
        int rt = t / 24, ct = t - rt * 24;
        f32x4 acc[4][4]; ZERO_ACC(acc);
        gemm_tile64(xsb, Dm, qW + (size_t)ct*64*Dm, Dm, rt*64, 16, acc, lane);
#pragma unroll
        for (int mi = 0; mi < 4; ++mi)
#pragma unroll
          for (int ni = 0; ni < 4; ++ni) {
            int col = ct*64 + ni*16 + l15;
            float cb = qb[col];
#pragma unroll
            for (int r = 0; r < 4; ++r) {
              int rw = rt*64 + mi*16 + q*4 + r;
              if (rw < BT) qkvbuf[(size_t)rw*1536 + col] = acc[mi][ni][r] + cb;
            }
          }
      }
    }
    gbar(bar);

    // ---- attention: block per (b,h), fp32 in LDS, writes obufb bf16 ----
    if (bid < 128) {
      const int b = bid >> 3, h = bid & 7;
      const float* base = qkvbuf + (size_t)b * NP1 * 1536 + h * 64;
      for (int idx = tid; idx < NP1 * 16; idx += 256) {
        int t = idx >> 4, c = (idx & 15) << 2;
        const float* pq = base + (size_t)t * 1536 + c;
        float4 q4 = *(const float4*)(pq);
        float4 k4 = *(const float4*)(pq + 512);
        sm.at.qv[t][c] = q4.x; sm.at.qv[t][c+1] = q4.y; sm.at.qv[t][c+2] = q4.z; sm.at.qv[t][c+3] = q4.w;
        sm.at.ks[t][c] = k4.x; sm.at.ks[t][c+1] = k4.y; sm.at.ks[t][c+2] = k4.z; sm.at.ks[t][c+3] = k4.w;
      }
      __syncthreads();
#pragma unroll
      for (int it = 0; it < 2; ++it) {
        int tile = it * 256 + tid;
        if (tile < 289) {
          int ti = (tile / 17) * 4, tj = (tile % 17) * 4;
          const float* qr[4]; const float* kr[4];
#pragma unroll
          for (int i = 0; i < 4; ++i) { qr[i] = sm.at.qv[min(ti+i,64)]; kr[i] = sm.at.ks[min(tj+i,64)]; }
          float acc[4][4] = {};
          for (int d = 0; d < 64; ++d) {
            float a[4], bv[4];
#pragma unroll
            for (int i = 0; i < 4; ++i) { a[i] = qr[i][d]; bv[i] = kr[i][d]; }
#pragma unroll
            for (int i = 0; i < 4; ++i)
#pragma unroll
              for (int j = 0; j < 4; ++j) acc[i][j] += a[i] * bv[j];
          }
#pragma unroll
          for (int i = 0; i < 4; ++i)
            if (ti + i < 65)
#pragma unroll
              for (int j = 0; j < 4; ++j)
                if (tj + j < 65) sm.at.ss[ti+i][tj+j] = acc[i][j] * 0.125f;
        }
      }
      __syncthreads();
      for (int idx = tid; idx < NP1 * 16; idx += 256) {
        int t = idx >> 4, c = (idx & 15) << 2;
        float4 v4 = *(const float4*)(base + (size_t)t * 1536 + 1024 + c);
        sm.at.qv[t][c] = v4.x; sm.at.qv[t][c+1] = v4.y; sm.at.qv[t][c+2] = v4.z; sm.at.qv[t][c+3] = v4.w;
      }
      if (tid < 65) {
        float mx = -1e30f;
        for (int j = 0; j < 65; ++j) mx = fmaxf(mx, sm.at.ss[tid][j]);
        float s = 0.f;
        for (int j = 0; j < 65; ++j) { float e = expf(sm.at.ss[tid][j] - mx); sm.at.ss[tid][j] = e; s += e; }
        float iv = 1.0f / s;
        for (int j = 0; j < 65; ++j) sm.at.ss[tid][j] *= iv;
      }
      __syncthreads();
#pragma unroll
      for (int it = 0; it < 2; ++it) {
        int tile = it * 256 + tid;
        if (tile < 272) {
          int ti = (tile >> 4) * 4, d0 = (tile & 15) * 4;
          const float* sr[4];
#pragma unroll
          for (int i = 0; i < 4; ++i) sr[i] = sm.at.ss[min(ti+i,64)];
          float acc[4][4] = {};
          for (int j = 0; j < 65; ++j) {
            float v0 = sm.at.qv[j][d0], v1 = sm.at.qv[j][d0+1];
            float v2 = sm.at.qv[j][d0+2], v3 = sm.at.qv[j][d0+3];
#pragma unroll
            for (int i = 0; i < 4; ++i) {
              float s = sr[i][j];
              acc[i][0] += s*v0; acc[i][1] += s*v1; acc[i][2] += s*v2; acc[i][3] += s*v3;
            }
          }
#pragma unroll
          for (int i = 0; i < 4; ++i)
            if (ti + i < 65) {
              ushort4 o;
              o.x = f2bf(acc[i][0]); o.y = f2bf(acc[i][1]);
              o.z = f2bf(acc[i][2]); o.w = f2bf(acc[i][3]);
              *(ushort4*)(obufb + (size_t)(b*NP1 + ti + i)*Dm + h*64 + d0) = o;
            }
        }
      }
    }
    gbar(bar);

    // ---- out-proj GEMM split-2: obufb x out_w^T -> part[0..1] ----
    {
      const u16* oW = wbf + 2359296 + (size_t)l * 262144;
      for (int t = gw; t < 272; t += NW) {
        int s = t / 136, rem = t - s * 136;
        int rt = rem / 8, ct = rem - rt * 8;
        f32x4 acc[4][4]; ZERO_ACC(acc);
        gemm_tile64(obufb + s*256, Dm, oW + (size_t)ct*64*Dm + s*256, Dm,
                    rt*64, 8, acc, lane);
        float* dst = part + (size_t)s * BT * Dm;
#pragma unroll
        for (int mi = 0; mi < 4; ++mi)
#pragma unroll
          for (int ni = 0; ni < 4; ++ni) {
            int col = ct*64 + ni*16 + l15;
#pragma unroll
            for (int r = 0; r < 4; ++r) {
              int rw = rt*64 + mi*16 + q*4 + r;
              if (rw < BT) dst[(size_t)rw*Dm + col] = acc[mi][ni][r];
            }
          }
      }
    }
    gbar(bar);

    // ---- ln1: xs = LN(xs + part0 + part1 + out_b) ----
    {
      const float* bias = out_b + l * Dm;
      const float* g = ln1_g + l * Dm;
      const float* bb = ln1_b + l * Dm;
      for (int t = gw; t < BT; t += NW) {
        int c0 = lane * 8;
        float v[8];
        float4 a0 = *(const float4*)(xs + (size_t)t*Dm + c0);
        float4 a1 = *(const float4*)(xs + (size_t)t*Dm + c0 + 4);
        float4 b0 = *(const float4*)(bias + c0), b1 = *(const float4*)(bias + c0 + 4);
        v[0]=a0.x+b0.x; v[1]=a0.y+b0.y; v[2]=a0.z+b0.z; v[3]=a0.w+b0.w;
        v[4]=a1.x+b1.x; v[5]=a1.y+b1.y; v[6]=a1.z+b1.z; v[7]=a1.w+b1.w;
#pragma unroll
        for (int s = 0; s < 2; ++s) {
          const float* pp = part + (size_t)s*BT*Dm + (size_t)t*Dm + c0;
          float4 q0 = *(const float4*)pp, q1 = *(const float4*)(pp + 4);
          v[0]+=q0.x; v[1]+=q0.y; v[2]+=q0.z; v[3]+=q0.w;
          v[4]+=q1.x; v[5]+=q1.y; v[6]+=q1.z; v[7]+=q1.w;
        }
        float s1 = 0.f;
#pragma unroll
        for (int j = 0; j < 8; ++j) s1 += v[j];
        float mu = wred(s1) * (1.0f/512.0f);
        float s2 = 0.f;
#pragma unroll
        for (int j = 0; j < 8; ++j) { float d = v[j]-mu; s2 += d*d; }
        float inv = rsqrtf(wred(s2) * (1.0f/512.0f) + 1e-5f);
        float4 g0 = *(const float4*)(g + c0), g1 = *(const float4*)(g + c0 + 4);
        float4 e0 = *(const float4*)(bb + c0), e1 = *(const float4*)(bb + c0 + 4);
        float gg[8] = {g0.x,g0.y,g0.z,g0.w,g1.x,g1.y,g1.z,g1.w};
        float ee[8] = {e0.x,e0.y,e0.z,e0.w,e1.x,e1.y,e1.z,e1.w};
        float y[8]; u16 yb[8];
#pragma unroll
        for (int j = 0; j < 8; ++j) { y[j] = (v[j]-mu)*inv*gg[j] + ee[j]; yb[j] = f2bf(y[j]); }
        *(float4*)(xs + (size_t)t*Dm + c0)     = make_float4(y[0],y[1],y[2],y[3]);
        *(float4*)(xs + (size_t)t*Dm + c0 + 4) = make_float4(y[4],y[5],y[6],y[7]);
        *(short8*)(xsb + (size_t)t*Dm + c0)    = *(short8*)yb;
      }
    }
    gbar(bar);

    // ---- ff1 GEMM: xsb x ff1_w^T, gelu -> ffb bf16 [1040,2048] ----
    {
      const u16* fW = wbf + 3145728 + (size_t)l * 1048576;
      const float* fb = ff1_b + l * 2048;
      for (int t = gw; t < 17 * 32; t += NW) {
        int rt = t / 32, ct = t - rt * 32;
        f32x4 acc[4][4]; ZERO_ACC(acc);
        gemm_tile64(xsb, Dm, fW + (size_t)ct*64*Dm, Dm, rt*64, 16, acc, lane);
#pragma unroll
        for (int mi = 0; mi < 4; ++mi)
#pragma unroll
          for (int ni = 0; ni < 4; ++ni) {
            int col = ct*64 + ni*16 + l15;
            float cb = fb[col];
#pragma unroll
            for (int r = 0; r < 4; ++r) {
              int rw = rt*64 + mi*16 + q*4 + r;
              if (rw < BT) ffb[(size_t)rw*2048 + col] = f2bf(gelu_exact(acc[mi][ni][r] + cb));
            }
          }
      }
    }
    gbar(bar);

    // ---- ff2 GEMM split-4: ffb x ff2_w^T -> part[0..3] ----
    {
      const u16* fW = wbf + 6291456 + (size_t)l * 1048576;
      for (int t = gw; t < 544; t += NW) {
        int s = t / 136, rem = t - s * 136;
        int rt = rem / 8, ct = rem - rt * 8;
        f32x4 acc[4][4]; ZERO_ACC(acc);
        gemm_tile64(ffb + s*512, 2048, fW + (size_t)ct*64*2048 + s*512, 2048,
                    rt*64, 16, acc, lane);
        float* dst = part + (size_t)s * BT * Dm;
#pragma unroll
        for (int mi = 0; mi < 4; ++mi)
#pragma unroll
          for (int ni = 0; ni < 4; ++ni) {
            int col = ct*64 + ni*16 + l15;
#pragma unroll
            for (int r = 0; r < 4; ++r) {
              int rw = rt*64 + mi*16 + q*4 + r;
              if (rw < BT) dst[(size_t)rw*Dm + col] = acc[mi][ni][r];
            }
          }
      }
    }
    gbar(bar);

    // ---- ln2: xs = LN(xs + part0..3 + ff2_b) ----
    {
      const float* bias = ff2_b + l * Dm;
      const float* g = ln2_g + l * Dm;
      const float* bb = ln2_b + l * Dm;
      for (int t = gw; t < BT; t += NW) {
        int c0 = lane * 8;
        float v[8];
        float4 a0 = *(const float4*)(xs + (size_t)t*Dm + c0);
        float4 a1 = *(const float4*)(xs + (size_t)t*Dm + c0 + 4);
        float4 b0 = *(const float4*)(bias + c0), b1 = *(const float4*)(bias + c0 + 4);
        v[0]=a0.x+b0.x; v[1]=a0.y+b0.y; v[2]=a0.z+b0.z; v[3]=a0.w+b0.w;
        v[4]=a1.x+b1.x; v[5]=a1.y+b1.y; v[6]=a1.z+b1.z; v[7]=a1.w+b1.w;
#pragma unroll
        for (int s = 0; s < 4; ++s) {
          const float* pp = part + (size_t)s*BT*Dm + (size_t)t*Dm + c0;
          float4 q0 = *(const float4*)pp, q1 = *(const float4*)(pp + 4);
          v[0]+=q0.x; v[1]+=q0.y; v[2]+=q0.z; v[3]+=q0.w;
          v[4]+=q1.x; v[5]+=q1.y; v[6]+=q1.z; v[7]+=q1.w;
        }
        float s1 = 0.f;
#pragma unroll
        for (int j = 0; j < 8; ++j) s1 += v[j];
        float mu = wred(s1) * (1.0f/512.0f);
        float s2 = 0.f;
#pragma unroll
        for (int j = 0; j < 8; ++j) { float d = v[j]-mu; s2 += d*d; }
        float inv = rsqrtf(wred(s2) * (1.0f/512.0f) + 1e-5f);
        float4 g0 = *(const float4*)(g + c0), g1 = *(const float4*)(g + c0 + 4);
        float4 e0 = *(const float4*)(bb + c0), e1 = *(const float4*)(bb + c0 + 4);
        float gg[8] = {g0.x,g0.y,g0.z,g0.w,g1.x,g1.y,g1.z,g1.w};
        float ee[8] = {e0.x,e0.y,e0.z,e0.w,e1.x,e1.y,e1.z,e1.w};
        float y[8]; u16 yb[8];
#pragma unroll
        for (int j = 0; j < 8; ++j) { y[j] = (v[j]-mu)*inv*gg[j] + ee[j]; yb[j] = f2bf(y[j]); }
        *(float4*)(xs + (size_t)t*Dm + c0)     = make_float4(y[0],y[1],y[2],y[3]);
        *(float4*)(xs + (size_t)t*Dm + c0 + 4) = make_float4(y[4],y[5],y[6],y[7]);
        *(short8*)(xsb + (size_t)t*Dm + c0)    = *(short8*)yb;
      }
    }
    gbar(bar);
  }

  // ===== u/h heads: xsb x uh_w^T (N=512: u cols 0..255, h cols 256..511) ====
  {
    const u16* uW = wbf + 9437184;
    for (int t = gw; t < 136; t += NW) {
      int rt = t / 8, ct = t - rt * 8;
      f32x4 acc[4][4]; ZERO_ACC(acc);
      gemm_tile64(xsb, Dm, uW + (size_t)ct*64*Dm, Dm, rt*64, 16, acc, lane);
#pragma unroll
      for (int mi = 0; mi < 4; ++mi)
#pragma unroll
        for (int ni = 0; ni < 4; ++ni) {
          int col = ct*64 + ni*16 + l15;
#pragma unroll
          for (int r = 0; r < 4; ++r) {
            int rw = rt*64 + mi*16 + q*4 + r;
            if (rw < BT) {
              float v = acc[mi][ni][r];
              if (col < 256) out_u[(size_t)rw*256 + col]        = v + u_b[col];
              else           hbuf[(size_t)rw*256 + (col - 256)] = v + h_b[col - 256];
            }
          }
        }
    }
  }
  gbar(bar);

  // ===== projection head (rank-1 softmax collapse) =====
  sm.xgs[tid] = xg[tid];
  __syncthreads();
  {
    int b = gw >> 6, n = gw & 63;
    int row = b * NP1 + n;
    int i0 = lane * 4;
    float4 a4 = *(const float4*)(hbuf + (size_t)row*MG + i0);
    float av[4] = {a4.x, a4.y, a4.z, a4.w};
    float num[4] = {}, den[4] = {}, m[4], na[4];
#pragma unroll
    for (int k = 0; k < 4; ++k) { m[k] = fabsf(av[k]) * 300.0f; na[k] = -av[k] * 100.0f; }
    for (int j = 0; j < 256; ++j) {
      float xj = sm.xgs[j];
#pragma unroll
      for (int k = 0; k < 4; ++k) {
        float w = expf(na[k] * xj - m[k]);
        num[k] += xj * w; den[k] += w;
      }
    }
    float4 mu4 = *(const float4*)(marg + (size_t)row*MG + i0);
    float muv[4] = {mu4.x, mu4.y, mu4.z, mu4.w};
    float wd = 0.f, ms = 0.f;
#pragma unroll
    for (int k = 0; k < 4; ++k) {
      float drift = num[k]/den[k] - sm.xgs[i0 + k];
      wd += muv[k] * drift; ms += muv[k];
    }
    wd = wred(wd); ms = wred(ms);
    float corr = wd / (ms + 1e-8f);
    *(float4*)(out_h + ((size_t)(b*64 + n))*MG + i0) =
        make_float4(av[0]-corr, av[1]-corr, av[2]-corr, av[3]-corr);
  }
}

// ---------------------------------------------------------------------------
extern "C" void kernel_launch(void* const* d_in, const int* in_sizes, int n_in,
                              void* d_out, int out_size, void* d_ws, size_t ws_size,
                              hipStream_t stream)
{
  const float* marg   = (const float*)d_in[0];
  const float* xg     = (const float*)d_in[1];
  const float* conv_w = (const float*)d_in[2];
  const float* conv_b = (const float*)d_in[3];
  const float* fc_w   = (const float*)d_in[4];
  const float* fc_b   = (const float*)d_in[5];
  const float* ln0_g  = (const float*)d_in[6];
  const float* ln0_b  = (const float*)d_in[7];
  const float* pos    = (const float*)d_in[8];
  const float* qkv_w  = (const float*)d_in[9];
  const float* qkv_b  = (const float*)d_in[10];
  const float* out_w  = (const float*)d_in[11];
  const float* out_b  = (const float*)d_in[12];
  const float* ln1_g  = (const float*)d_in[13];
  const float* ln1_b  = (const float*)d_in[14];
  const float* ff1_w  = (const float*)d_in[15];
  const float* ff1_b  = (const float*)d_in[16];
  const float* ff2_w  = (const float*)d_in[17];
  const float* ff2_b  = (const float*)d_in[18];
  const float* ln2_g  = (const float*)d_in[19];
  const float* ln2_b  = (const float*)d_in[20];
  const float* u_w    = (const float*)d_in[21];
  const float* u_b    = (const float*)d_in[22];
  const float* h_w    = (const float*)d_in[23];
  const float* h_b    = (const float*)d_in[24];
  float* out = (float*)d_out;

  float* ws = (float*)d_ws;
  float* xs      = ws;                              // 532480
  float* qkvbuf  = ws + 532480;                     // 1597440
  float* part    = ws + 2129920;                    // 4 x 532480
  float* hbuf    = ws + 4259840;                    // 266240
  u16*   xsb     = (u16*)(ws + 4526080);            // 532480 u16
  u16*   obufb   = (u16*)(ws + 4792320);            // 532480 u16
  u16*   ffb     = (u16*)(ws + 5058560);            // 2129920 u16
  u16*   wbf     = (u16*)(ws + 6123520);            // 9699328 u16 (ends 10973184 fl)
  unsigned* bar  = (unsigned*)((char*)d_ws + (size_t)48 * 1024 * 1024);

  hipMemsetAsync(bar, 0, 16, stream);
  cvt_weights<<<2048, 256, 0, stream>>>(qkv_w, out_w, ff1_w, ff2_w, u_w, h_w, wbf);
  mega<<<NBLK, 256, 0, stream>>>(
      marg, xg, conv_w, conv_b, fc_w, fc_b, ln0_g, ln0_b, pos,
      qkv_b, out_b, ln1_g, ln1_b, ff1_b, ff2_b, ln2_g, ln2_b, u_b, h_b,
      wbf, xs, xsb, qkvbuf, obufb, ffb, part, hbuf,
      out, out + 1040*256, bar);
}

// Round 5
// 553.383 us; speedup vs baseline: 4.7474x; 4.7474x over previous
//
#include <hip/hip_runtime.h>
#include <math.h>

// ---------------------------------------------------------------------------
// B=16, NP1=65, BT=1040 tokens, Mg=256, D=512, H=8, DH=64, L=3, DFF=2048
// R5: back to multi-kernel (R4 persistent/grid-barrier design regressed 5.7x:
// cross-XCD barrier polling ~100us each with all pipes idle). GEMMs upgraded
// to the m97 structure: 128x128 tile, BK=64, global_load_lds(16B),
// 32 MFMA/wave per barrier pair.
// ---------------------------------------------------------------------------

#define BT   1040
#define NP1  65
#define Dm   512
#define MG   256

typedef short short8 __attribute__((ext_vector_type(8)));
typedef float f32x4  __attribute__((ext_vector_type(4)));
typedef unsigned short u16;

__device__ __forceinline__ u16 f2bf(float f) {
  unsigned int u = __float_as_uint(f);
  u += 0x7FFF + ((u >> 16) & 1);          // RNE
  return (u16)(u >> 16);
}

__device__ __forceinline__ float gelu_exact(float x) {
  return 0.5f * x * (1.0f + erff(x * 0.70710678118654752f));
}

__device__ __forceinline__ void async16(const u16* g, u16* l) {
  __builtin_amdgcn_global_load_lds(
      (const __attribute__((address_space(1))) unsigned int*)g,
      (__attribute__((address_space(3))) unsigned int*)l, 16, 0, 0);
}

__device__ __forceinline__ float block_reduce_sum(float v, float* s) {
#pragma unroll
  for (int off = 32; off; off >>= 1) v += __shfl_down(v, off, 64);
  int lane = threadIdx.x & 63, wid = threadIdx.x >> 6;
  __syncthreads();
  if (lane == 0) s[wid] = v;
  __syncthreads();
  return s[0] + s[1] + s[2] + s[3];
}

// ---------------------------------------------------------------------------
// Weight fp32 -> bf16 (u16 offsets: qkv 0 | out 2359296 | ff1 3145728 |
// ff2 6291456 | uh 9437184 | total 9699328)
// ---------------------------------------------------------------------------
__global__ __launch_bounds__(256) void cvt_weights(
    const float* __restrict__ qkv_w, const float* __restrict__ out_w,
    const float* __restrict__ ff1_w, const float* __restrict__ ff2_w,
    const float* __restrict__ u_w,   const float* __restrict__ h_w,
    u16* __restrict__ dst)
{
  const size_t O1 = 2359296, O2 = 3145728, O3 = 6291456;
  const size_t O4 = 9437184, O5 = 9568256, TOT4 = 9699328 / 4;
  for (size_t e4 = (size_t)blockIdx.x * 256 + threadIdx.x; e4 < TOT4;
       e4 += (size_t)gridDim.x * 256) {
    size_t e = e4 * 4;
    const float* src;
    if      (e < O1) src = qkv_w + e;
    else if (e < O2) src = out_w + (e - O1);
    else if (e < O3) src = ff1_w + (e - O2);
    else if (e < O4) src = ff2_w + (e - O3);
    else if (e < O5) src = u_w   + (e - O4);
    else             src = h_w   + (e - O5);
    float4 v = *(const float4*)src;
    unsigned int lo = (unsigned int)f2bf(v.x) | ((unsigned int)f2bf(v.y) << 16);
    unsigned int hi = (unsigned int)f2bf(v.z) | ((unsigned int)f2bf(v.w) << 16);
    *(uint2*)(dst + e) = make_uint2(lo, hi);
  }
}

// ---------------------------------------------------------------------------
// Fused: conv+mean (collapsed) -> fc(128->512) -> LN -> GELU -> +pos
// ---------------------------------------------------------------------------
__global__ __launch_bounds__(256) void embed_kernel(
    const float* __restrict__ marg, const float* __restrict__ conv_w,
    const float* __restrict__ conv_b, const float* __restrict__ fc_w,
    const float* __restrict__ fc_b, const float* __restrict__ g,
    const float* __restrict__ bb, const float* __restrict__ pos,
    float* __restrict__ xs, u16* __restrict__ xsb)
{
  __shared__ float es[128];
  __shared__ float red[4];
  int t = blockIdx.x, tid = threadIdx.x;
  const float* row = marg + (size_t)t * MG;
  float S = block_reduce_sum(row[tid], red);
  float x0 = row[0], x1 = row[1], x254 = row[254], x255 = row[255];
  if (tid < 128) {
    int o = tid;
    float w0 = conv_w[o*5+0], w1 = conv_w[o*5+1], w2 = conv_w[o*5+2];
    float w3 = conv_w[o*5+3], w4 = conv_w[o*5+4];
    float acc = w0*(S - x254 - x255) + w1*(S - x255) + w2*S
              + w3*(S - x0) + w4*(S - x0 - x1);
    es[o] = acc * (1.0f/256.0f) + conv_b[o];
  }
  __syncthreads();
  float z0 = fc_b[tid], z1 = fc_b[tid + 256];
#pragma unroll 4
  for (int o = 0; o < 128; ++o) {
    float e = es[o];
    z0 += e * fc_w[(size_t)o*Dm + tid];
    z1 += e * fc_w[(size_t)o*Dm + tid + 256];
  }
  float mu = block_reduce_sum(z0 + z1, red) * (1.0f/512.0f);
  float d0 = z0 - mu, d1 = z1 - mu;
  float var = block_reduce_sum(d0*d0 + d1*d1, red) * (1.0f/512.0f);
  float inv = rsqrtf(var + 1e-5f);
  float y0 = gelu_exact(d0*inv*g[tid]     + bb[tid])     + pos[(size_t)(t%NP1)*Dm + tid];
  float y1 = gelu_exact(d1*inv*g[tid+256] + bb[tid+256]) + pos[(size_t)(t%NP1)*Dm + tid + 256];
  xs[(size_t)t*Dm + tid]        = y0;
  xs[(size_t)t*Dm + tid + 256]  = y1;
  xsb[(size_t)t*Dm + tid]       = f2bf(y0);
  xsb[(size_t)t*Dm + tid + 256] = f2bf(y1);
}

// ---------------------------------------------------------------------------
// MFMA GEMM (m97 structure): BM=BN=128, BK=64. Both operands bf16 staged via
// global_load_lds width=16. 4 waves in 2x2: wave tile 64x64 = 4x4 16x16 frags,
// 32 MFMA per wave per K-iter. LDS chunk-major (c=k/8):
//   elem (c,r) at (c*128 + r)*8 u16  -> all ds ops b128-sequential, 0 conflicts.
// Fragment (verified R2-R3): lane=(q<<4)|l15 holds [m|n=l15][k=32t+8q+j].
// MODE: 0 fp32 v+bias | 1 bf16 gelu(v+bias) | 2 fp32 partial | 3 u/h dual head
// ---------------------------------------------------------------------------
template<int SPLITS, int MODE>
__global__ __launch_bounds__(256) void gemm_mfma(
    const u16* __restrict__ A, const u16* __restrict__ Bw,
    const float* __restrict__ bias, float* __restrict__ Cf,
    u16* __restrict__ Cb, float* __restrict__ C2,
    const float* __restrict__ bias2, int Mrows, int N, int K)
{
  __shared__ u16 Asl[8*128*8];   // 16 KB
  __shared__ u16 Bsl[8*128*8];   // 16 KB
  const int tid  = threadIdx.x;
  const int row0 = blockIdx.y * 128;
  const int col0 = blockIdx.x * 128;
  const int Ks   = K / SPLITS;
  const int kbase = (int)blockIdx.z * Ks;
  const int lane = tid & 63;
  const int wave = tid >> 6;
  const int wm = (wave >> 1) * 64;
  const int wn = (wave & 1) * 64;
  const int l15 = lane & 15;
  const int q   = lane >> 4;

  f32x4 acc[4][4];
#pragma unroll
  for (int i = 0; i < 4; ++i)
#pragma unroll
    for (int j = 0; j < 4; ++j) acc[i][j] = (f32x4){0.f, 0.f, 0.f, 0.f};

  const int arow = min(row0 + lane, Mrows - 1);        // per-lane A row base
  const int arow2 = min(row0 + 64 + lane, Mrows - 1);

  for (int k0 = kbase; k0 < kbase + Ks; k0 += 64) {
    __syncthreads();
    // A: 16 stages of 1KB (c 0..7 x half 0..1), 4 per wave
#pragma unroll
    for (int i = 0; i < 4; ++i) {
      int idx = wave * 4 + i;          // 0..15
      int c = idx >> 1, s = idx & 1;
      int r = s ? arow2 : arow;
      async16(A + (size_t)r * K + k0 + c * 8,
              &Asl[(size_t)(c * 128 + s * 64) * 8]);
    }
    // B: 16 stages of 1KB, 4 per wave (N is a multiple of 128 for all shapes)
#pragma unroll
    for (int i = 0; i < 4; ++i) {
      int idx = wave * 4 + i;
      int c = idx >> 1, s = idx & 1;
      async16(Bw + (size_t)(col0 + s * 64 + lane) * K + k0 + c * 8,
              &Bsl[(size_t)(c * 128 + s * 64) * 8]);
    }
    __syncthreads();                   // drains vmcnt(0), then barrier
#pragma unroll
    for (int t = 0; t < 2; ++t) {
      int cc = t * 4 + q;
      short8 af[4], bf[4];
#pragma unroll
      for (int mi = 0; mi < 4; ++mi)
        af[mi] = *(short8*)&Asl[(size_t)(cc*128 + wm + mi*16 + l15) * 8];
#pragma unroll
      for (int ni = 0; ni < 4; ++ni)
        bf[ni] = *(short8*)&Bsl[(size_t)(cc*128 + wn + ni*16 + l15) * 8];
#pragma unroll
      for (int mi = 0; mi < 4; ++mi)
#pragma unroll
        for (int ni = 0; ni < 4; ++ni)
          acc[mi][ni] = __builtin_amdgcn_mfma_f32_16x16x32_bf16(
              af[mi], bf[ni], acc[mi][ni], 0, 0, 0);
    }
  }

  float* Cp = Cf;
  if (MODE == 2) Cp += (size_t)blockIdx.z * (size_t)Mrows * N;
#pragma unroll
  for (int mi = 0; mi < 4; ++mi) {
#pragma unroll
    for (int ni = 0; ni < 4; ++ni) {
      int col = col0 + wn + ni*16 + l15;
#pragma unroll
      for (int r = 0; r < 4; ++r) {
        int row = row0 + wm + mi*16 + q*4 + r;
        if (row < Mrows) {
          float v = acc[mi][ni][r];
          if (MODE == 0) {
            Cp[(size_t)row*N + col] = v + bias[col];
          } else if (MODE == 1) {
            Cb[(size_t)row*N + col] = f2bf(gelu_exact(v + bias[col]));
          } else if (MODE == 2) {
            Cp[(size_t)row*N + col] = v;
          } else {  // MODE 3: u/h dual head
            if (col < 256) Cf[(size_t)row*256 + col]         = v + bias[col];
            else           C2[(size_t)row*256 + (col - 256)] = v + bias2[col - 256];
          }
        }
      }
    }
  }
}

// ---------------------------------------------------------------------------
// Attention: one block per (b,h); fp32 in LDS; writes obuf bf16
// ---------------------------------------------------------------------------
__global__ __launch_bounds__(256) void attn_kernel(
    const float* __restrict__ qkv, u16* __restrict__ obufb)
{
  __shared__ float qv[65][67];
  __shared__ float ks[65][67];
  __shared__ float ss[65][67];
  const int b = blockIdx.x >> 3, h = blockIdx.x & 7;
  const int tid = threadIdx.x;
  const float* base = qkv + (size_t)b * NP1 * 1536 + h * 64;
  for (int idx = tid; idx < NP1 * 16; idx += 256) {
    int t = idx >> 4, c = (idx & 15) << 2;
    const float* p = base + (size_t)t * 1536 + c;
    float4 q4 = *(const float4*)(p);
    float4 k4 = *(const float4*)(p + 512);
    qv[t][c] = q4.x; qv[t][c+1] = q4.y; qv[t][c+2] = q4.z; qv[t][c+3] = q4.w;
    ks[t][c] = k4.x; ks[t][c+1] = k4.y; ks[t][c+2] = k4.z; ks[t][c+3] = k4.w;
  }
  __syncthreads();
#pragma unroll
  for (int it = 0; it < 2; ++it) {
    int tile = it * 256 + tid;
    if (tile < 289) {
      int ti = (tile / 17) * 4, tj = (tile % 17) * 4;
      const float* qr[4]; const float* kr[4];
#pragma unroll
      for (int i = 0; i < 4; ++i) { qr[i] = qv[min(ti + i, 64)]; kr[i] = ks[min(tj + i, 64)]; }
      float acc[4][4] = {};
      for (int d = 0; d < 64; ++d) {
        float a[4], bvv[4];
#pragma unroll
        for (int i = 0; i < 4; ++i) { a[i] = qr[i][d]; bvv[i] = kr[i][d]; }
#pragma unroll
        for (int i = 0; i < 4; ++i)
#pragma unroll
          for (int j = 0; j < 4; ++j) acc[i][j] += a[i] * bvv[j];
      }
#pragma unroll
      for (int i = 0; i < 4; ++i)
        if (ti + i < 65)
#pragma unroll
          for (int j = 0; j < 4; ++j)
            if (tj + j < 65) ss[ti + i][tj + j] = acc[i][j] * 0.125f;
    }
  }
  __syncthreads();
  for (int idx = tid; idx < NP1 * 16; idx += 256) {
    int t = idx >> 4, c = (idx & 15) << 2;
    float4 v4 = *(const float4*)(base + (size_t)t * 1536 + 1024 + c);
    qv[t][c] = v4.x; qv[t][c+1] = v4.y; qv[t][c+2] = v4.z; qv[t][c+3] = v4.w;
  }
  if (tid < 65) {
    float mx = -1e30f;
    for (int j = 0; j < 65; ++j) mx = fmaxf(mx, ss[tid][j]);
    float s = 0.0f;
    for (int j = 0; j < 65; ++j) { float e = expf(ss[tid][j] - mx); ss[tid][j] = e; s += e; }
    float inv = 1.0f / s;
    for (int j = 0; j < 65; ++j) ss[tid][j] *= inv;
  }
  __syncthreads();
#pragma unroll
  for (int it = 0; it < 2; ++it) {
    int tile = it * 256 + tid;
    if (tile < 272) {
      int ti = (tile >> 4) * 4, d0 = (tile & 15) * 4;
      const float* sr[4];
#pragma unroll
      for (int i = 0; i < 4; ++i) sr[i] = ss[min(ti + i, 64)];
      float acc[4][4] = {};
      for (int j = 0; j < 65; ++j) {
        float v0 = qv[j][d0], v1 = qv[j][d0+1], v2 = qv[j][d0+2], v3 = qv[j][d0+3];
#pragma unroll
        for (int i = 0; i < 4; ++i) {
          float s = sr[i][j];
          acc[i][0] += s * v0; acc[i][1] += s * v1;
          acc[i][2] += s * v2; acc[i][3] += s * v3;
        }
      }
#pragma unroll
      for (int i = 0; i < 4; ++i)
        if (ti + i < 65) {
          ushort4 o;
          o.x = f2bf(acc[i][0]); o.y = f2bf(acc[i][1]);
          o.z = f2bf(acc[i][2]); o.w = f2bf(acc[i][3]);
          *(ushort4*)(obufb + (size_t)(b * NP1 + ti + i) * Dm + h * 64 + d0) = o;
        }
    }
  }
}

// ---------------------------------------------------------------------------
// xs = LN(xs + sum_s part[s] + bias); writes fp32 + bf16 mirror
// ---------------------------------------------------------------------------
template<int S>
__global__ __launch_bounds__(256) void add_ln_multi(
    float* __restrict__ xs, u16* __restrict__ xsb,
    const float* __restrict__ part, const float* __restrict__ bias,
    const float* __restrict__ g, const float* __restrict__ bb)
{
  __shared__ float red[4];
  int t = blockIdx.x, tid = threadIdx.x;
  float* xp = xs + (size_t)t * Dm;
  float v0 = xp[tid] + bias[tid];
  float v1 = xp[tid + 256] + bias[tid + 256];
#pragma unroll
  for (int s = 0; s < S; ++s) {
    const float* pp = part + (size_t)s * BT * Dm + (size_t)t * Dm;
    v0 += pp[tid]; v1 += pp[tid + 256];
  }
  float mu = block_reduce_sum(v0 + v1, red) * (1.0f/512.0f);
  float d0 = v0 - mu, d1 = v1 - mu;
  float var = block_reduce_sum(d0*d0 + d1*d1, red) * (1.0f/512.0f);
  float inv = rsqrtf(var + 1e-5f);
  float y0 = d0 * inv * g[tid]       + bb[tid];
  float y1 = d1 * inv * g[tid + 256] + bb[tid + 256];
  xp[tid]       = y0;
  xp[tid + 256] = y1;
  xsb[(size_t)t*Dm + tid]       = f2bf(y0);
  xsb[(size_t)t*Dm + tid + 256] = f2bf(y1);
}

// ---------------------------------------------------------------------------
// Projection head (rank-1 softmax collapse)
// ---------------------------------------------------------------------------
__global__ __launch_bounds__(256) void proj_kernel(
    const float* __restrict__ hbuf, const float* __restrict__ marg,
    const float* __restrict__ xg, float* __restrict__ out_h)
{
  __shared__ float xgs[256];
  __shared__ float red[4];
  int n = blockIdx.x, b = blockIdx.y, i = threadIdx.x;
  xgs[i] = xg[i];
  __syncthreads();
  int row = b * NP1 + n;
  float a = hbuf[(size_t)row * MG + i];
  const float inv_eps = 100.0f;
  float m = fabsf(a) * 3.0f * inv_eps;
  float num = 0.0f, den = 0.0f;
  float na = -a * inv_eps;
#pragma unroll 4
  for (int j = 0; j < 256; ++j) {
    float xj = xgs[j];
    float w = expf(na * xj - m);
    num += xj * w; den += w;
  }
  float drift = num / den - xgs[i];
  float mu = marg[(size_t)row * MG + i];
  float wd = block_reduce_sum(mu * drift, red);
  float ms = block_reduce_sum(mu, red);
  float corr = wd / (ms + 1e-8f);
  out_h[((size_t)(b * 64 + n)) * MG + i] = a - corr;
}

// ---------------------------------------------------------------------------
extern "C" void kernel_launch(void* const* d_in, const int* in_sizes, int n_in,
                              void* d_out, int out_size, void* d_ws, size_t ws_size,
                              hipStream_t stream)
{
  const float* marg   = (const float*)d_in[0];
  const float* xg     = (const float*)d_in[1];
  const float* conv_w = (const float*)d_in[2];
  const float* conv_b = (const float*)d_in[3];
  const float* fc_w   = (const float*)d_in[4];
  const float* fc_b   = (const float*)d_in[5];
  const float* ln0_g  = (const float*)d_in[6];
  const float* ln0_b  = (const float*)d_in[7];
  const float* pos    = (const float*)d_in[8];
  const float* qkv_w  = (const float*)d_in[9];
  const float* qkv_b  = (const float*)d_in[10];
  const float* out_w  = (const float*)d_in[11];
  const float* out_b  = (const float*)d_in[12];
  const float* ln1_g  = (const float*)d_in[13];
  const float* ln1_b  = (const float*)d_in[14];
  const float* ff1_w  = (const float*)d_in[15];
  const float* ff1_b  = (const float*)d_in[16];
  const float* ff2_w  = (const float*)d_in[17];
  const float* ff2_b  = (const float*)d_in[18];
  const float* ln2_g  = (const float*)d_in[19];
  const float* ln2_b  = (const float*)d_in[20];
  const float* u_w    = (const float*)d_in[21];
  const float* u_b    = (const float*)d_in[22];
  const float* h_w    = (const float*)d_in[23];
  const float* h_b    = (const float*)d_in[24];
  float* out = (float*)d_out;

  float* ws = (float*)d_ws;
  float* xs      = ws;                              // 532480
  float* qkvbuf  = ws + 532480;                     // 1597440
  float* part    = ws + 2129920;                    // 4 x 532480
  float* hbuf    = ws + 4259840;                    // 266240
  u16*   xsb     = (u16*)(ws + 4526080);            // 532480 u16
  u16*   obufb   = (u16*)(ws + 4792320);            // 532480 u16
  u16*   ffb     = (u16*)(ws + 5058560);            // 2129920 u16
  u16*   wbf     = (u16*)(ws + 6123520);            // 9699328 u16

  const u16* qkv_bw = wbf;
  const u16* out_bw = wbf + 2359296;
  const u16* ff1_bw = wbf + 3145728;
  const u16* ff2_bw = wbf + 6291456;
  const u16* uh_bw  = wbf + 9437184;   // u rows 0..255, h rows 256..511

  cvt_weights<<<304, 256, 0, stream>>>(qkv_w, out_w, ff1_w, ff2_w, u_w, h_w, wbf);
  embed_kernel<<<BT, 256, 0, stream>>>(marg, conv_w, conv_b, fc_w, fc_b,
                                       ln0_g, ln0_b, pos, xs, xsb);

  for (int l = 0; l < 3; ++l) {
    gemm_mfma<1,0><<<dim3(12, 9, 1), 256, 0, stream>>>(
        xsb, qkv_bw + (size_t)l*786432, qkv_b + l*1536, qkvbuf,
        nullptr, nullptr, nullptr, BT, 1536, 512);
    attn_kernel<<<128, 256, 0, stream>>>(qkvbuf, obufb);
    gemm_mfma<2,2><<<dim3(4, 9, 2), 256, 0, stream>>>(
        obufb, out_bw + (size_t)l*262144, nullptr, part,
        nullptr, nullptr, nullptr, BT, 512, 512);
    add_ln_multi<2><<<BT, 256, 0, stream>>>(xs, xsb, part, out_b + l*512,
                                            ln1_g + l*512, ln1_b + l*512);
    gemm_mfma<1,1><<<dim3(16, 9, 1), 256, 0, stream>>>(
        xsb, ff1_bw + (size_t)l*1048576, ff1_b + l*2048, nullptr,
        ffb, nullptr, nullptr, BT, 2048, 512);
    gemm_mfma<4,2><<<dim3(4, 9, 4), 256, 0, stream>>>(
        ffb, ff2_bw + (size_t)l*1048576, nullptr, part,
        nullptr, nullptr, nullptr, BT, 512, 2048);
    add_ln_multi<4><<<BT, 256, 0, stream>>>(xs, xsb, part, ff2_b + l*512,
                                            ln2_g + l*512, ln2_b + l*512);
  }

  gemm_mfma<1,3><<<dim3(4, 9, 1), 256, 0, stream>>>(
      xsb, uh_bw, u_b, out, nullptr, hbuf, h_b, BT, 512, 512);
  proj_kernel<<<dim3(64, 16), 256, 0, stream>>>(hbuf, marg, xg, out + 1040*256);
}